// Round 11
// baseline (4390.887 us; speedup 1.0000x reference)
//
#include <hip/hip_runtime.h>
#include <hip/hip_bf16.h>
#include <math.h>
#include <stdint.h>

// RNN LM forward: B=64 T=512 V=8192 E=1024 H=2048
// out = [logits (B*T*V f32) | loss (1 f32)]
#define Bb 64
#define Tt 512
#define Vv 8192
#define Ee 1024
#define Hh 2048

typedef unsigned short u16;
typedef unsigned long long u64;
typedef __attribute__((ext_vector_type(8))) short bf16x8;      // 8x16b (4 VGPR)
typedef __attribute__((ext_vector_type(8))) _Float16 f16x8;    // 8 f16  (4 VGPR)
typedef __attribute__((ext_vector_type(4))) float f32x4;       // MFMA C/D frag

__device__ __forceinline__ u16 f2b(float f) {               // f32 -> bf16 RNE
  unsigned u = __float_as_uint(f);
  u += 0x7FFF + ((u >> 16) & 1);
  return (u16)(u >> 16);
}
__device__ __forceinline__ float b2f(u16 h) {
  return __uint_as_float(((unsigned)h) << 16);
}
__device__ __forceinline__ u16 f2h_bits(float f) {          // f32 -> f16 bits
  union { _Float16 h; u16 u; } c;
  c.h = (_Float16)f;
  return c.u;
}

// pipelined agent-coherent 16B load (sc1 = bypass XCD-L2, read L3 directly)
__device__ __forceinline__ void gload16f(f16x8& dst, const void* addr) {
  asm volatile("global_load_dwordx4 %0, %1, off sc1"
               : "=v"(dst) : "v"(addr) : "memory");
}
// agent-coherent 2B store (same semantics as relaxed agent atomic store)
__device__ __forceinline__ void gstore2_sc1(void* addr, unsigned val) {
  asm volatile("global_store_short %0, %1, off sc1"
               :: "v"(addr), "v"(val) : "memory");
}

__device__ __forceinline__ void gll16(const u16* g, const u16* l) {
  __builtin_amdgcn_global_load_lds((__attribute__((address_space(1))) void*)g,
                                   (__attribute__((address_space(3))) void*)l, 16, 0, 0);
}

__device__ __forceinline__ float wave_max(float v) {
  #pragma unroll
  for (int d = 32; d; d >>= 1) v = fmaxf(v, __shfl_xor(v, d, 64));
  return v;
}
__device__ __forceinline__ float wave_sum(float v) {
  #pragma unroll
  for (int d = 32; d; d >>= 1) v += __shfl_xor(v, d, 64);
  return v;
}

// ---------------- prep kernels ----------------

// gather W_E rows by idx -> f16 (r10-proven: f16 emb err ~1e-5 abs on xproj,
// far below the head-GEMM quantization floor)
__global__ __launch_bounds__(256)
void embed_cast_f16(const float* __restrict__ WE, const int* __restrict__ idx,
                    u16* __restrict__ emb) {
  const int m = blockIdx.x;
  const int row = idx[m];
  const float4 v = ((const float4*)(WE + (size_t)row * Ee))[threadIdx.x];
  ushort4 o;
  o.x = f2h_bits(v.x); o.y = f2h_bits(v.y);
  o.z = f2h_bits(v.z); o.w = f2h_bits(v.w);
  ((ushort4*)(emb + (size_t)m * Ee))[threadIdx.x] = o;
}

// src[R][C] f32 -> dst[C][R] f16 bits (transpose + f16 cast) — Wx, Wh, Whead
__global__ __launch_bounds__(256)
void transpose_cast_f16(const float* __restrict__ src, u16* __restrict__ dst,
                        int R, int C) {
  __shared__ float tile[32][33];
  const int bi = blockIdx.x;
  const int bj = blockIdx.y;
  const int tid = threadIdx.x;
  const int r  = tid >> 3;
  const int c4 = (tid & 7) * 4;
  float4 v = *(const float4*)(src + (size_t)(bj * 32 + r) * C + bi * 32 + c4);
  tile[r][c4 + 0] = v.x; tile[r][c4 + 1] = v.y;
  tile[r][c4 + 2] = v.z; tile[r][c4 + 3] = v.w;
  __syncthreads();
  ushort4 o;
  o.x = f2h_bits(tile[c4 + 0][r]); o.y = f2h_bits(tile[c4 + 1][r]);
  o.z = f2h_bits(tile[c4 + 2][r]); o.w = f2h_bits(tile[c4 + 3][r]);
  *(ushort4*)(dst + (size_t)(bi * 32 + r) * R + bj * 32 + c4) = o;
}

__global__ __launch_bounds__(256)
void h0_init(const float* __restrict__ start, u16* __restrict__ hbuf) {
  const int b = blockIdx.x;
  #pragma unroll
  for (int j = 0; j < 8; ++j) {
    int n = threadIdx.x * 8 + j;
    hbuf[(size_t)b * 2048 + n] = f2h_bits(start[n]);
  }
}

// ---------------- GEMM (m97-style 128x128 tile, BK=32, 4 waves) ----------------
// C[M x N] = A[M x K] * Bt[N x K]^T, f32 accum. F16 selects f16 vs bf16 MFMA.
// MODE 0: out f32 at [row*N+col] + bias (head GEMM -> logits in d_out),
//         PLUS fused per-row softmax partials pm/ps[row][bn].
// MODE 1: out bf16 at [(t*B+b)*N+col] + bias, row = b*T+t  (xproj, t-major)
// XCD-aware block swizzle (T1): nwg % 8 == 0 for both call sites.
template <int MODE, int F16>
__global__ __launch_bounds__(256, 2)
void gemm_bt(const u16* __restrict__ A, const u16* __restrict__ Bt,
             const float* __restrict__ bias, void* __restrict__ outp,
             float* __restrict__ pm, float* __restrict__ ps,
             int M, int N, int K) {
  __shared__ u16 ldsA[128 * 32];
  __shared__ u16 ldsB[128 * 32];
  __shared__ float sm_[2][2][64];   // [wc][wr][row_local]  (MODE 0 partials)
  __shared__ float ss_[2][2][64];
  const int tid = threadIdx.x;
  const int lane = tid & 63;
  const int w = tid >> 6;
  const int wr = w >> 1, wc = w & 1;

  const int nwg = gridDim.x * gridDim.y;
  const int lin = blockIdx.y * gridDim.x + blockIdx.x;
  const int swz = (lin & 7) * (nwg >> 3) + (lin >> 3);
  const int bm = swz % gridDim.x;
  const int bn = swz / gridDim.x;

  const int srow = w * 32 + (lane >> 2);
  const int scol = (lane & 3) * 8;
  const u16* a0 = A + (size_t)(bm * 128 + srow) * K + scol;
  const u16* b0 = Bt + (size_t)(bn * 128 + srow) * K + scol;
  u16* lA0 = ldsA + w * 1024;
  u16* lA1 = ldsA + w * 1024 + 512;
  u16* lB0 = ldsB + w * 1024;
  u16* lB1 = ldsB + w * 1024 + 512;

  f32x4 acc[4][4];
  #pragma unroll
  for (int m = 0; m < 4; ++m)
    #pragma unroll
    for (int n = 0; n < 4; ++n)
      acc[m][n] = (f32x4){0.f, 0.f, 0.f, 0.f};

  const int nk = K >> 5;
  for (int kt = 0; kt < nk; ++kt) {
    __syncthreads();
    const u16* ak = a0 + kt * 32;
    const u16* bk = b0 + kt * 32;
    gll16(ak, lA0);
    gll16(ak + 16 * (size_t)K, lA1);
    gll16(bk, lB0);
    gll16(bk + 16 * (size_t)K, lB1);
    __syncthreads();
    bf16x8 af[4], bfr[4];
    #pragma unroll
    for (int i = 0; i < 4; ++i) {
      af[i]  = *(const bf16x8*)&ldsA[(wr * 64 + i * 16 + (lane & 15)) * 32 + (lane >> 4) * 8];
      bfr[i] = *(const bf16x8*)&ldsB[(wc * 64 + i * 16 + (lane & 15)) * 32 + (lane >> 4) * 8];
    }
    #pragma unroll
    for (int m = 0; m < 4; ++m)
      #pragma unroll
      for (int n = 0; n < 4; ++n) {
        if (F16) {
          acc[m][n] = __builtin_amdgcn_mfma_f32_16x16x32_f16(
              *(const f16x8*)&af[m], *(const f16x8*)&bfr[n], acc[m][n], 0, 0, 0);
        } else {
          acc[m][n] = __builtin_amdgcn_mfma_f32_16x16x32_bf16(af[m], bfr[n], acc[m][n], 0, 0, 0);
        }
      }
  }

  // epilogue: D col = lane&15, row = (lane>>4)*4 + q
  const int r0 = bm * 128 + wr * 64 + (lane >> 4) * 4;
  const int c0 = bn * 128 + wc * 64 + (lane & 15);

  if (MODE == 0) {
    float bv[4];
    #pragma unroll
    for (int n = 0; n < 4; ++n) bv[n] = bias[c0 + n * 16];
    #pragma unroll
    for (int m = 0; m < 4; ++m) {
      #pragma unroll
      for (int q = 0; q < 4; ++q) {
        const int row = r0 + m * 16 + q;
        float v[4];
        float mx = -1e30f;
        #pragma unroll
        for (int n = 0; n < 4; ++n) {
          v[n] = acc[m][n][q] + bv[n];
          ((float*)outp)[(size_t)row * N + c0 + n * 16] = v[n];
          mx = fmaxf(mx, v[n]);
        }
        #pragma unroll
        for (int d = 1; d < 16; d <<= 1) mx = fmaxf(mx, __shfl_xor(mx, d, 64));
        float se = 0.f;
        #pragma unroll
        for (int n = 0; n < 4; ++n) se += expf(v[n] - mx);
        #pragma unroll
        for (int d = 1; d < 16; d <<= 1) se += __shfl_xor(se, d, 64);
        if ((lane & 15) == 0) {
          const int rl = m * 16 + (lane >> 4) * 4 + q;
          sm_[wc][wr][rl] = mx;
          ss_[wc][wr][rl] = se;
        }
      }
    }
    __syncthreads();
    if (w < 2) {   // wave w combines wc halves for rows [bm*128 + w*64, +64)
      float m0 = sm_[0][w][lane], m1 = sm_[1][w][lane];
      float s0 = ss_[0][w][lane], s1 = ss_[1][w][lane];
      float Mx = fmaxf(m0, m1);
      float S = s0 * expf(m0 - Mx) + s1 * expf(m1 - Mx);
      const int row = bm * 128 + w * 64 + lane;
      pm[(size_t)row * 64 + bn] = Mx;
      ps[(size_t)row * 64 + bn] = S;
    }
  } else {
    #pragma unroll
    for (int n = 0; n < 4; ++n) {
      const int col = c0 + n * 16;
      const float bv = bias[col];
      #pragma unroll
      for (int m = 0; m < 4; ++m) {
        #pragma unroll
        for (int q = 0; q < 4; ++q) {
          const int row = r0 + m * 16 + q;
          float v = acc[m][n][q] + bv;
          const int b = row >> 9, t = row & 511;   // row = b*T + t
          ((u16*)outp)[((size_t)t * Bb + b) * N + col] = f2b(v);
        }
      }
    }
  }
}

// ---------------- persistent recurrence scan ----------------
// 256 blocks x 512 thr (8 waves), 1 block/CU (144KB LDS). Wh f16 in LDS for
// all 512 steps; h = single f16 stream, ping-pong in global via sc1.
// Sync (A/B-measured r2-r8): relaxed single monotonic counter, poll the
// counter itself; agent acq/rel = L2 wb/inv (never in hot loop); flag arrays
// and arrival trees both regress.  r11: poll loop adds s_sleep(1) backoff
// (64 pollers hammer the same L3 line the arrival RMWs land on).
// r11: epilogue split across ALL 8 waves (1 value/lane, 1 tanh/lane) —
// was waves 0-1 with a serial 4-tanh chain while 6 waves idled.
// hidden now stored f16 (head GEMM runs f16 MFMA — higher precision, same rate).
__global__ __launch_bounds__(512, 2)
void rnn_scan(const u16* __restrict__ WhT, const u16* __restrict__ xp,
              u16* __restrict__ hbuf, u16* __restrict__ hidden,
              unsigned* __restrict__ sync) {
  __shared__ u16 whi[65536];     // 128KB f16 bits: frag(c2,kt) base (c2*64+kt)*512 u16
  __shared__ float red[4096];    // 16KB: 16 slots x 256 f32

  const int bid = blockIdx.x;
  const int g = bid >> 6;
  const int colg = bid & 63;
  const int rowbase = g * 16;
  const int col0 = colg * 32;
  const int tid = threadIdx.x;
  const int lane = tid & 63;
  const int w = tid >> 6;

  for (int i = tid; i < 8192; i += 512) {
    const int ch = i & 3;
    const int cl = (i >> 2) & 15;
    const int kt = (i >> 6) & 63;
    const int c2 = (i >> 12) & 1;
    bf16x8 v = *(const bf16x8*)(WhT + (size_t)(col0 + c2 * 16 + cl) * 2048 + kt * 32 + ch * 8);
    *(bf16x8*)&whi[(size_t)(c2 * 64 + kt) * 512 + ch * 128 + cl * 8] = v;
  }
  __syncthreads();

  unsigned* cnt = sync + g * 64;
  bool dead = false;
  const int hrow = rowbase + (lane & 15);

  // epilogue assignment (t-invariant): value v = w*64+lane -> frag f, pos p
  const int ev = w * 64 + lane;
  const int ef = ev >> 8;
  const int ep = ev & 255;
  const int el = ep >> 2, eq = ep & 3;
  const int erow = rowbase + (el & 15);
  const int ecol = col0 + ef * 16 + ((el >> 4) << 2) + eq;

  // xp prefetch for t=0 (1 bf16 per lane)
  u16 xv16 = xp[(size_t)erow * 2048 + ecol];

  for (int t = 0; t < Tt; ++t) {
    const u16* hp = hbuf + (size_t)(t & 1) * (64 * 2048);
    u16*       hn = hbuf + (size_t)((t + 1) & 1) * (64 * 2048);

    // ---- batched h loads for this wave's K-slice: 8 x 16B, all in flight ----
    f16x8 qh[8];
    const u16* hb = hp + (size_t)hrow * 2048 + (lane >> 4) * 8;
    #pragma unroll
    for (int kt = 0; kt < 8; ++kt)
      gload16f(qh[kt], hb + (w * 8 + kt) * 32);
    asm volatile("s_waitcnt vmcnt(0)" ::: "memory");
    __builtin_amdgcn_sched_barrier(0);   // rule #18: pin MFMAs below the waitcnt

    f32x4 a0 = (f32x4){0.f, 0.f, 0.f, 0.f};
    f32x4 a1 = (f32x4){0.f, 0.f, 0.f, 0.f};
    #pragma unroll
    for (int kt = 0; kt < 8; ++kt) {
      const int ktG = w * 8 + kt;
      f16x8 w0 = *(const f16x8*)&whi[(size_t)(0 * 64 + ktG) * 512 + (lane >> 4) * 128 + (lane & 15) * 8];
      f16x8 w1 = *(const f16x8*)&whi[(size_t)(1 * 64 + ktG) * 512 + (lane >> 4) * 128 + (lane & 15) * 8];
      a0 = __builtin_amdgcn_mfma_f32_16x16x32_f16(w0, qh[kt], a0, 0, 0, 0);
      a1 = __builtin_amdgcn_mfma_f32_16x16x32_f16(w1, qh[kt], a1, 0, 0, 0);
    }

    // ---- K-reduce: all waves export both frags ----
    *(f32x4*)&red[(w) * 256 + lane * 4]     = a0;   // frag0 bank: slots 0..7
    *(f32x4*)&red[(8 + w) * 256 + lane * 4] = a1;   // frag1 bank: slots 8..15
    __syncthreads();

    // ---- epilogue: all 8 waves, 1 value/lane (1 tanh) ----
    {
      float s = 0.f;
      #pragma unroll
      for (int j = 0; j < 8; ++j)
        s += red[(ef * 8 + j) * 256 + ep];
      float hv = tanhf(s + b2f(xv16));
      u16 hf = f2h_bits(hv);
      gstore2_sc1(hn + (size_t)erow * 2048 + ecol, (unsigned)hf);
      hidden[((size_t)erow * Tt + t) * Hh + ecol] = hf;
    }

    // ---- group barrier: relaxed monotonic counter, poll with backoff ----
    __syncthreads();                    // drains vmcnt -> h stores complete at L3
    if (t + 1 < Tt)                     // prefetch next xp (overlaps poll)
      xv16 = xp[((size_t)(t + 1) * Bb + erow) * 2048 + ecol];
    if (tid == 0) {
      unsigned old = __hip_atomic_fetch_add(cnt, 1u, __ATOMIC_RELAXED, __HIP_MEMORY_SCOPE_AGENT);
      if (old != (unsigned)(t * 64 + 63) && !dead) {   // not the last arriver
        unsigned polls = 0;
        while (__hip_atomic_load(cnt, __ATOMIC_RELAXED, __HIP_MEMORY_SCOPE_AGENT)
               < (unsigned)((t + 1) * 64)) {
          __builtin_amdgcn_s_sleep(1);                 // throttle L3 line traffic
          if (++polls > 1000000u) { dead = true; break; }   // anti-hang escape
        }
      }
    }
    __syncthreads();
  }
}

// ---------------- loss ----------------

__global__ __launch_bounds__(256)
void nll_from_partials(const float* __restrict__ pm, const float* __restrict__ ps,
                       const float* __restrict__ logits, const int* __restrict__ tgt,
                       float* __restrict__ nll) {
  const int r = blockIdx.x * 4 + (threadIdx.x >> 6);
  const int lane = threadIdx.x & 63;
  float m = pm[(size_t)r * 64 + lane];
  float s = ps[(size_t)r * 64 + lane];
  float M = wave_max(m);
  float S = wave_sum(s * expf(m - M));
  if (lane == 0) {
    const int tg = tgt[r];
    float o = 0.f;
    if (tg != -1) o = M + logf(S) - logits[(size_t)r * Vv + tg];
    nll[r] = o;
  }
}

__global__ __launch_bounds__(256)
void loss_reduce(const float* __restrict__ nll, const int* __restrict__ tgt,
                 float* __restrict__ out) {
  const int tid = threadIdx.x;
  float s = 0.f, c = 0.f;
  for (int i = tid; i < Bb * Tt; i += 256) {
    s += nll[i];
    c += (tgt[i] != -1) ? 1.f : 0.f;
  }
  s = wave_sum(s);
  c = wave_sum(c);
  __shared__ float as_[4], ac_[4];
  const int w = tid >> 6;
  if ((tid & 63) == 0) { as_[w] = s; ac_[w] = c; }
  __syncthreads();
  if (tid == 0) {
    float S = as_[0] + as_[1] + as_[2] + as_[3];
    float C = ac_[0] + ac_[1] + ac_[2] + ac_[3];
    out[0] = S / fmaxf(C, 1.f);
  }
}

// ---------------- launch ----------------

extern "C" void kernel_launch(void* const* d_in, const int* in_sizes, int n_in,
                              void* d_out, int out_size, void* d_ws, size_t ws_size,
                              hipStream_t stream) {
  const int*   idx    = (const int*)d_in[0];
  const int*   tgt    = (const int*)d_in[1];
  const float* W_E    = (const float*)d_in[2];
  const float* start  = (const float*)d_in[3];
  const float* W_xh   = (const float*)d_in[4];
  const float* b_xh   = (const float*)d_in[5];
  const float* W_head = (const float*)d_in[6];
  const float* b_head = (const float*)d_in[7];

  // workspace layout (~314 MB). emb16 (dead after xproj GEMM) aliases hidden.
  // pm/ps (head-GEMM softmax partials) alias xproj (dead after rnn_scan).
  char* ws = (char*)d_ws;
  u16*      emb16  = (u16*)(ws);                                  // 32768x1024 f16 = 64MB
  u16*      hidden = (u16*)(ws);                                  // 32768x2048 f16 = 128MB (alias)
  u16*      xproj  = (u16*)(ws + (size_t)128 * 1024 * 1024);      // [T][B][H] bf16 = 128MB
  float*    pm     = (float*)(ws + (size_t)128 * 1024 * 1024);    // 32768x64 f32 = 8MB (alias)
  float*    ps     = (float*)(ws + (size_t)136 * 1024 * 1024);    // 32768x64 f32 = 8MB (alias)
  u16*      WheadT = (u16*)(ws + (size_t)256 * 1024 * 1024);      // 8192x2048 f16 = 32MB
  u16*      WhT    = (u16*)(ws + (size_t)288 * 1024 * 1024);      // 2048x2048 f16 = 8MB
  u16*      WxT16  = (u16*)(ws + (size_t)304 * 1024 * 1024);      // 2048x1024 f16 = 4MB
  u16*      hbuf   = (u16*)(ws + (size_t)312 * 1024 * 1024);      // 2x64x2048 f16 = 512KB
  float*    nll    = (float*)(ws + (size_t)313 * 1024 * 1024);    // 32768 f32
  unsigned* sync   = (unsigned*)(ws + (size_t)313 * 1024 * 1024 + 128 * 1024);

  embed_cast_f16<<<Bb * Tt, 256, 0, stream>>>(W_E, idx, emb16);
  transpose_cast_f16<<<dim3(Hh / 32, Ee / 32), 256, 0, stream>>>(W_xh, WxT16, Ee, Hh);
  transpose_cast_f16<<<dim3(Hh / 32, Hh / 32), 256, 0, stream>>>(W_xh + (size_t)Ee * Hh, WhT, Hh, Hh);
  transpose_cast_f16<<<dim3(Vv / 32, Hh / 32), 256, 0, stream>>>(W_head, WheadT, Hh, Vv);
  h0_init<<<Bb, 256, 0, stream>>>(start, hbuf);
  hipMemsetAsync(sync, 0, 1024, stream);

  // xproj = emb_f16 @ Wx_f16 + b_xh   (K=1024, f16 MFMA, out bf16 t-major)
  gemm_bt<1, 1><<<dim3(256, 16), 256, 0, stream>>>(emb16, WxT16, b_xh, xproj, nullptr, nullptr,
                                                   Bb * Tt, Hh, 1024);

  // persistent scan: 256 blocks (1/CU), 512 threads, Wh resident in LDS (f16)
  rnn_scan<<<256, 512, 0, stream>>>(WhT, xproj, hbuf, hidden, sync);

  // logits = hidden_f16 @ Whead_f16 + b_head -> d_out, + fused softmax partials
  gemm_bt<0, 1><<<dim3(256, 64), 256, 0, stream>>>(hidden, WheadT, b_head, d_out, pm, ps,
                                                   Bb * Tt, Vv, 2048);

  nll_from_partials<<<Bb * Tt / 4, 256, 0, stream>>>(pm, ps, (const float*)d_out, tgt, nll);
  loss_reduce<<<1, 256, 0, stream>>>(nll, tgt, (float*)d_out + ((size_t)out_size - 1));
}

// Round 12
// 4172.041 us; speedup vs baseline: 1.0525x; 1.0525x over previous
//
#include <hip/hip_runtime.h>
#include <hip/hip_bf16.h>
#include <math.h>
#include <stdint.h>

// RNN LM forward: B=64 T=512 V=8192 E=1024 H=2048
// out = [logits (B*T*V f32) | loss (1 f32)]
#define Bb 64
#define Tt 512
#define Vv 8192
#define Ee 1024
#define Hh 2048

typedef unsigned short u16;
typedef unsigned long long u64;
typedef __attribute__((ext_vector_type(8))) short bf16x8;      // 8x16b (4 VGPR)
typedef __attribute__((ext_vector_type(8))) _Float16 f16x8;    // 8 f16  (4 VGPR)
typedef __attribute__((ext_vector_type(4))) float f32x4;       // MFMA C/D frag

__device__ __forceinline__ u16 f2b(float f) {               // f32 -> bf16 RNE
  unsigned u = __float_as_uint(f);
  u += 0x7FFF + ((u >> 16) & 1);
  return (u16)(u >> 16);
}
__device__ __forceinline__ float b2f(u16 h) {
  return __uint_as_float(((unsigned)h) << 16);
}
__device__ __forceinline__ u16 f2h_bits(float f) {          // f32 -> f16 bits
  union { _Float16 h; u16 u; } c;
  c.h = (_Float16)f;
  return c.u;
}

// pipelined agent-coherent 16B load (sc1 = bypass XCD-L2, read L3 directly)
__device__ __forceinline__ void gload16f(f16x8& dst, const void* addr) {
  asm volatile("global_load_dwordx4 %0, %1, off sc1"
               : "=v"(dst) : "v"(addr) : "memory");
}
// agent-coherent 2B store (same semantics as relaxed agent atomic store)
__device__ __forceinline__ void gstore2_sc1(void* addr, unsigned val) {
  asm volatile("global_store_short %0, %1, off sc1"
               :: "v"(addr), "v"(val) : "memory");
}

__device__ __forceinline__ void gll16(const u16* g, const u16* l) {
  __builtin_amdgcn_global_load_lds((__attribute__((address_space(1))) void*)g,
                                   (__attribute__((address_space(3))) void*)l, 16, 0, 0);
}

__device__ __forceinline__ float wave_max(float v) {
  #pragma unroll
  for (int d = 32; d; d >>= 1) v = fmaxf(v, __shfl_xor(v, d, 64));
  return v;
}
__device__ __forceinline__ float wave_sum(float v) {
  #pragma unroll
  for (int d = 32; d; d >>= 1) v += __shfl_xor(v, d, 64);
  return v;
}

// ---------------- prep kernels ----------------

__global__ __launch_bounds__(256)
void embed_cast_f16(const float* __restrict__ WE, const int* __restrict__ idx,
                    u16* __restrict__ emb) {
  const int m = blockIdx.x;
  const int row = idx[m];
  const float4 v = ((const float4*)(WE + (size_t)row * Ee))[threadIdx.x];
  ushort4 o;
  o.x = f2h_bits(v.x); o.y = f2h_bits(v.y);
  o.z = f2h_bits(v.z); o.w = f2h_bits(v.w);
  ((ushort4*)(emb + (size_t)m * Ee))[threadIdx.x] = o;
}

// src[R][C] f32 -> dst[C][R] f16 bits (transpose + f16 cast) — Wx, Wh, Whead
__global__ __launch_bounds__(256)
void transpose_cast_f16(const float* __restrict__ src, u16* __restrict__ dst,
                        int R, int C) {
  __shared__ float tile[32][33];
  const int bi = blockIdx.x;
  const int bj = blockIdx.y;
  const int tid = threadIdx.x;
  const int r  = tid >> 3;
  const int c4 = (tid & 7) * 4;
  float4 v = *(const float4*)(src + (size_t)(bj * 32 + r) * C + bi * 32 + c4);
  tile[r][c4 + 0] = v.x; tile[r][c4 + 1] = v.y;
  tile[r][c4 + 2] = v.z; tile[r][c4 + 3] = v.w;
  __syncthreads();
  ushort4 o;
  o.x = f2h_bits(tile[c4 + 0][r]); o.y = f2h_bits(tile[c4 + 1][r]);
  o.z = f2h_bits(tile[c4 + 2][r]); o.w = f2h_bits(tile[c4 + 3][r]);
  *(ushort4*)(dst + (size_t)(bi * 32 + r) * R + bj * 32 + c4) = o;
}

__global__ __launch_bounds__(256)
void h0_init(const float* __restrict__ start, u16* __restrict__ hbuf) {
  const int b = blockIdx.x;
  #pragma unroll
  for (int j = 0; j < 8; ++j) {
    int n = threadIdx.x * 8 + j;
    hbuf[(size_t)b * 2048 + n] = f2h_bits(start[n]);
  }
}

// ---------------- GEMM: 256x256 tile, BK=32, quad-buffered counted pipeline ----
// C[M x N] = A[M x K] * Bt[N x K]^T, f16/bf16 in, f32 accum. 512 thr = 8 waves
// (2M x 4N), per-wave 128x64 out (acc[8][4]). LDS 128KB = 4 buffers x (A 16KB +
// B 16KB). Per K-tile (BK=32): 2 phases (C row-half x K=32, 16 MFMA each).
// Stage tile t+3 during tile t (A halves in ph0, B in ph1) -> write-to-read gap
// = 4-6 phases; target buffer (t+3)&3 = (t-1)&3 was last read at tile t-1,
// retired at the preceding phase-ending barrier (r9's race structurally
// impossible). vmcnt(8) = 2 loads/phase x 4 stage-pairs in flight; forces tile
// t's stages (issued t-3) landed by end of tile t-1 — one tile BEFORE use.
// Tail (no staging): vmcnt(0). LDS layout per tile: [16-row-block][K-granule
// g=0..3][row%16] x 16B — the linear DMA order IS this layout (dest base
// uniform per wave, lane = g*16+row%15), and frag reads are 256B-contiguous
// per 16 lanes -> conflict-free without XOR swizzle.
// MODE 0: f32 out + bias + fused softmax partials pm/ps[row][bn] (bn = N/256).
// MODE 1: bf16 out t-major [(t*B+b)*N+col] + bias, row = b*T+t.
template <int MODE, int F16>
__global__ __launch_bounds__(512, 2)
void gemm256(const u16* __restrict__ A, const u16* __restrict__ Bt,
             const float* __restrict__ bias, void* __restrict__ outp,
             float* __restrict__ pm, float* __restrict__ ps,
             int M, int N, int K) {
  __shared__ u16 lds[65536];   // 128KB: A buf b at b*8192, B buf b at 32768+b*8192

  const int tid = threadIdx.x;
  const int lane = tid & 63;
  const int w = tid >> 6;          // wave 0..7
  const int wm = w >> 2;           // 0..1 (M half)
  const int wn = w & 3;            // 0..3 (N quarter)
  const int l15 = lane & 15, l16 = lane >> 4;

  // XCD-aware swizzle (nwg % 8 == 0 at both call sites)
  const int nwg = gridDim.x * gridDim.y;
  const int lin = blockIdx.y * gridDim.x + blockIdx.x;
  const int swz = (lin & 7) * (nwg >> 3) + (lin >> 3);
  const int bm = swz % gridDim.x;
  const int bn = swz / gridDim.x;
  const int bm256 = bm * 256, bn256 = bn * 256;

  // staging: wave w covers row-blocks w and 8+w; lane: row = rb*16 + l15,
  // granule g = l16. src u16 = (R0+rb*16+l15)*K + kt*32 + l16*8.
  // dest = buf + rb*512 (wave-uniform; HW adds lane*16B = g*256B + l15*16B).
  const size_t srcLane = (size_t)l15 * K + l16 * 8;
  #define STG(P, R0, kt, base)                                                 \
    {                                                                          \
      gll16((P) + (size_t)((R0) + w * 16) * K + (size_t)(kt) * 32 + srcLane,   \
            &lds[(base) + w * 512]);                                           \
      gll16((P) + (size_t)((R0) + (8 + w) * 16) * K + (size_t)(kt) * 32 + srcLane, \
            &lds[(base) + (8 + w) * 512]);                                     \
    }
  // frag read: tile-local row base rbase (mult of 16), lane offsets (l15,l16)
  #define DSF(base, rbase) \
    (*(const bf16x8*)&lds[(base) + ((rbase) >> 4) * 512 + l16 * 128 + l15 * 8])
  #define MM1(a, b, c)                                                          \
    (F16 ? __builtin_amdgcn_mfma_f32_16x16x32_f16(*(const f16x8*)&(a),          \
                                                  *(const f16x8*)&(b), (c), 0, 0, 0) \
         : __builtin_amdgcn_mfma_f32_16x16x32_bf16((a), (b), (c), 0, 0, 0))

  f32x4 acc[8][4];
  #pragma unroll
  for (int m = 0; m < 8; ++m)
    #pragma unroll
    for (int n = 0; n < 4; ++n)
      acc[m][n] = (f32x4){0.f, 0.f, 0.f, 0.f};

  const int NT = K >> 5;           // K-tiles (64 head, 32 xproj; both %4==0)

  // prologue: stage tiles 0,1,2 into buffers 0,1,2
  for (int pt = 0; pt < 3; ++pt) {
    STG(A,  bm256, pt, pt * 8192);
    STG(Bt, bn256, pt, 32768 + pt * 8192);
  }
  asm volatile("s_waitcnt vmcnt(0)" ::: "memory");
  __builtin_amdgcn_s_barrier();

  for (int t = 0; t < NT; ++t) {
    const int abase = (t & 3) * 8192;
    const int bbase = 32768 + (t & 3) * 8192;
    const int sb = (t + 3) & 3;
    const bool stg = (t + 3 < NT);
    bf16x8 aR[4], bR[4];

    // ---- phase 0: B frags + A row-half 0, stage A of tile t+3 ----
    #pragma unroll
    for (int j = 0; j < 4; ++j) bR[j] = DSF(bbase, wn * 64 + j * 16);
    #pragma unroll
    for (int i = 0; i < 4; ++i) aR[i] = DSF(abase, wm * 128 + i * 16);
    if (stg) {
      STG(A, bm256, t + 3, sb * 8192);
      asm volatile("s_waitcnt vmcnt(8)" ::: "memory");
    } else {
      asm volatile("s_waitcnt vmcnt(0)" ::: "memory");
    }
    __builtin_amdgcn_s_barrier();
    asm volatile("s_waitcnt lgkmcnt(0)" ::: "memory");
    __builtin_amdgcn_sched_barrier(0);
    __builtin_amdgcn_s_setprio(1);
    #pragma unroll
    for (int i = 0; i < 4; ++i)
      #pragma unroll
      for (int j = 0; j < 4; ++j)
        acc[i][j] = MM1(aR[i], bR[j], acc[i][j]);
    __builtin_amdgcn_s_setprio(0);
    __builtin_amdgcn_s_barrier();

    // ---- phase 1: A row-half 1 (B frags reused from regs), stage B of t+3 ----
    #pragma unroll
    for (int i = 0; i < 4; ++i) aR[i] = DSF(abase, wm * 128 + 64 + i * 16);
    if (stg) {
      STG(Bt, bn256, t + 3, 32768 + sb * 8192);
      asm volatile("s_waitcnt vmcnt(8)" ::: "memory");
    } else {
      asm volatile("s_waitcnt vmcnt(0)" ::: "memory");
    }
    __builtin_amdgcn_s_barrier();
    asm volatile("s_waitcnt lgkmcnt(0)" ::: "memory");
    __builtin_amdgcn_sched_barrier(0);
    __builtin_amdgcn_s_setprio(1);
    #pragma unroll
    for (int i = 0; i < 4; ++i)
      #pragma unroll
      for (int j = 0; j < 4; ++j)
        acc[4 + i][j] = MM1(aR[i], bR[j], acc[4 + i][j]);
    __builtin_amdgcn_s_setprio(0);
    __builtin_amdgcn_s_barrier();
  }

  // ---- epilogue (last barrier passed; LDS reusable) ----
  // D frag: row = base + l16*4 + q, col = base + l15 (m89-verified layout)
  const int c0 = bn256 + wn * 64 + l15;
  float bv[4];
  #pragma unroll
  for (int j = 0; j < 4; ++j) bv[j] = bias[c0 + j * 16];

  if (MODE == 0) {
    float* scr = (float*)lds;        // [0..1024) max, [1024..2048) sumexp
    float* outf = (float*)outp;
    #pragma unroll
    for (int fm = 0; fm < 8; ++fm) {
      #pragma unroll
      for (int q = 0; q < 4; ++q) {
        const int rl = wm * 128 + (fm >> 2) * 64 + (fm & 3) * 16 + l16 * 4 + q;
        const int row = bm256 + rl;
        float v0 = acc[fm][0][q] + bv[0];
        float v1 = acc[fm][1][q] + bv[1];
        float v2 = acc[fm][2][q] + bv[2];
        float v3 = acc[fm][3][q] + bv[3];
        outf[(size_t)row * N + c0]      = v0;
        outf[(size_t)row * N + c0 + 16] = v1;
        outf[(size_t)row * N + c0 + 32] = v2;
        outf[(size_t)row * N + c0 + 48] = v3;
        float mx = fmaxf(fmaxf(v0, v1), fmaxf(v2, v3));
        #pragma unroll
        for (int d = 1; d < 16; d <<= 1) mx = fmaxf(mx, __shfl_xor(mx, d, 64));
        float se = expf(v0 - mx) + expf(v1 - mx) + expf(v2 - mx) + expf(v3 - mx);
        #pragma unroll
        for (int d = 1; d < 16; d <<= 1) se += __shfl_xor(se, d, 64);
        if (l15 == 0) {
          scr[wn * 256 + rl] = mx;
          scr[1024 + wn * 256 + rl] = se;
        }
      }
    }
    __syncthreads();
    if (lane < 32) {
      const int rl = w * 32 + lane;
      float m0 = scr[rl], m1 = scr[256 + rl], m2 = scr[512 + rl], m3 = scr[768 + rl];
      float Mx = fmaxf(fmaxf(m0, m1), fmaxf(m2, m3));
      float S = scr[1024 + rl] * expf(m0 - Mx) + scr[1280 + rl] * expf(m1 - Mx)
              + scr[1536 + rl] * expf(m2 - Mx) + scr[1792 + rl] * expf(m3 - Mx);
      const int row = bm256 + rl;
      const int nbn = N >> 8;
      pm[(size_t)row * nbn + bn] = Mx;
      ps[(size_t)row * nbn + bn] = S;
    }
  } else {
    u16* outh = (u16*)outp;
    #pragma unroll
    for (int fm = 0; fm < 8; ++fm) {
      #pragma unroll
      for (int q = 0; q < 4; ++q) {
        const int row = bm256 + wm * 128 + (fm >> 2) * 64 + (fm & 3) * 16 + l16 * 4 + q;
        const int b = row >> 9, t = row & 511;   // row = b*T + t
        u16* dst = outh + ((size_t)t * Bb + b) * N + c0;
        dst[0]  = f2b(acc[fm][0][q] + bv[0]);
        dst[16] = f2b(acc[fm][1][q] + bv[1]);
        dst[32] = f2b(acc[fm][2][q] + bv[2]);
        dst[48] = f2b(acc[fm][3][q] + bv[3]);
      }
    }
  }
  #undef STG
  #undef DSF
  #undef MM1
}

// ---------------- persistent recurrence scan (r11, unchanged) ----------------
__global__ __launch_bounds__(512, 2)
void rnn_scan(const u16* __restrict__ WhT, const u16* __restrict__ xp,
              u16* __restrict__ hbuf, u16* __restrict__ hidden,
              unsigned* __restrict__ sync) {
  __shared__ u16 whi[65536];     // 128KB f16 bits: frag(c2,kt) base (c2*64+kt)*512 u16
  __shared__ float red[4096];    // 16KB: 16 slots x 256 f32

  const int bid = blockIdx.x;
  const int g = bid >> 6;
  const int colg = bid & 63;
  const int rowbase = g * 16;
  const int col0 = colg * 32;
  const int tid = threadIdx.x;
  const int lane = tid & 63;
  const int w = tid >> 6;

  for (int i = tid; i < 8192; i += 512) {
    const int ch = i & 3;
    const int cl = (i >> 2) & 15;
    const int kt = (i >> 6) & 63;
    const int c2 = (i >> 12) & 1;
    bf16x8 v = *(const bf16x8*)(WhT + (size_t)(col0 + c2 * 16 + cl) * 2048 + kt * 32 + ch * 8);
    *(bf16x8*)&whi[(size_t)(c2 * 64 + kt) * 512 + ch * 128 + cl * 8] = v;
  }
  __syncthreads();

  unsigned* cnt = sync + g * 64;
  bool dead = false;
  const int hrow = rowbase + (lane & 15);

  const int ev = w * 64 + lane;
  const int ef = ev >> 8;
  const int ep = ev & 255;
  const int el = ep >> 2, eq = ep & 3;
  const int erow = rowbase + (el & 15);
  const int ecol = col0 + ef * 16 + ((el >> 4) << 2) + eq;

  u16 xv16 = xp[(size_t)erow * 2048 + ecol];

  for (int t = 0; t < Tt; ++t) {
    const u16* hp = hbuf + (size_t)(t & 1) * (64 * 2048);
    u16*       hn = hbuf + (size_t)((t + 1) & 1) * (64 * 2048);

    f16x8 qh[8];
    const u16* hb = hp + (size_t)hrow * 2048 + (lane >> 4) * 8;
    #pragma unroll
    for (int kt = 0; kt < 8; ++kt)
      gload16f(qh[kt], hb + (w * 8 + kt) * 32);
    asm volatile("s_waitcnt vmcnt(0)" ::: "memory");
    __builtin_amdgcn_sched_barrier(0);

    f32x4 a0 = (f32x4){0.f, 0.f, 0.f, 0.f};
    f32x4 a1 = (f32x4){0.f, 0.f, 0.f, 0.f};
    #pragma unroll
    for (int kt = 0; kt < 8; ++kt) {
      const int ktG = w * 8 + kt;
      f16x8 w0 = *(const f16x8*)&whi[(size_t)(0 * 64 + ktG) * 512 + (lane >> 4) * 128 + (lane & 15) * 8];
      f16x8 w1 = *(const f16x8*)&whi[(size_t)(1 * 64 + ktG) * 512 + (lane >> 4) * 128 + (lane & 15) * 8];
      a0 = __builtin_amdgcn_mfma_f32_16x16x32_f16(w0, qh[kt], a0, 0, 0, 0);
      a1 = __builtin_amdgcn_mfma_f32_16x16x32_f16(w1, qh[kt], a1, 0, 0, 0);
    }

    *(f32x4*)&red[(w) * 256 + lane * 4]     = a0;
    *(f32x4*)&red[(8 + w) * 256 + lane * 4] = a1;
    __syncthreads();

    {
      float s = 0.f;
      #pragma unroll
      for (int j = 0; j < 8; ++j)
        s += red[(ef * 8 + j) * 256 + ep];
      float hv = tanhf(s + b2f(xv16));
      u16 hf = f2h_bits(hv);
      gstore2_sc1(hn + (size_t)erow * 2048 + ecol, (unsigned)hf);
      hidden[((size_t)erow * Tt + t) * Hh + ecol] = hf;
    }

    __syncthreads();
    if (t + 1 < Tt)
      xv16 = xp[((size_t)(t + 1) * Bb + erow) * 2048 + ecol];
    if (tid == 0) {
      unsigned old = __hip_atomic_fetch_add(cnt, 1u, __ATOMIC_RELAXED, __HIP_MEMORY_SCOPE_AGENT);
      if (old != (unsigned)(t * 64 + 63) && !dead) {
        unsigned polls = 0;
        while (__hip_atomic_load(cnt, __ATOMIC_RELAXED, __HIP_MEMORY_SCOPE_AGENT)
               < (unsigned)((t + 1) * 64)) {
          __builtin_amdgcn_s_sleep(1);
          if (++polls > 1000000u) { dead = true; break; }
        }
      }
    }
    __syncthreads();
  }
}

// ---------------- loss ----------------

// per-row NLL from fused GEMM partials (32 bn-tiles at 256-wide head GEMM)
__global__ __launch_bounds__(256)
void nll_from_partials(const float* __restrict__ pm, const float* __restrict__ ps,
                       const float* __restrict__ logits, const int* __restrict__ tgt,
                       float* __restrict__ nll) {
  const int r = blockIdx.x * 4 + (threadIdx.x >> 6);
  const int lane = threadIdx.x & 63;
  float m = (lane < 32) ? pm[(size_t)r * 32 + lane] : -1e30f;
  float s = (lane < 32) ? ps[(size_t)r * 32 + lane] : 0.f;
  float M = wave_max(m);
  float S = wave_sum(s * expf(m - M));
  if (lane == 0) {
    const int tg = tgt[r];
    float o = 0.f;
    if (tg != -1) o = M + logf(S) - logits[(size_t)r * Vv + tg];
    nll[r] = o;
  }
}

__global__ __launch_bounds__(256)
void loss_reduce(const float* __restrict__ nll, const int* __restrict__ tgt,
                 float* __restrict__ out) {
  const int tid = threadIdx.x;
  float s = 0.f, c = 0.f;
  for (int i = tid; i < Bb * Tt; i += 256) {
    s += nll[i];
    c += (tgt[i] != -1) ? 1.f : 0.f;
  }
  s = wave_sum(s);
  c = wave_sum(c);
  __shared__ float as_[4], ac_[4];
  const int w = tid >> 6;
  if ((tid & 63) == 0) { as_[w] = s; ac_[w] = c; }
  __syncthreads();
  if (tid == 0) {
    float S = as_[0] + as_[1] + as_[2] + as_[3];
    float C = ac_[0] + ac_[1] + ac_[2] + ac_[3];
    out[0] = S / fmaxf(C, 1.f);
  }
}

// ---------------- launch ----------------

extern "C" void kernel_launch(void* const* d_in, const int* in_sizes, int n_in,
                              void* d_out, int out_size, void* d_ws, size_t ws_size,
                              hipStream_t stream) {
  const int*   idx    = (const int*)d_in[0];
  const int*   tgt    = (const int*)d_in[1];
  const float* W_E    = (const float*)d_in[2];
  const float* start  = (const float*)d_in[3];
  const float* W_xh   = (const float*)d_in[4];
  const float* b_xh   = (const float*)d_in[5];
  const float* W_head = (const float*)d_in[6];
  const float* b_head = (const float*)d_in[7];

  // workspace layout (~314 MB). emb16 (dead after xproj GEMM) aliases hidden.
  // pm/ps (head-GEMM softmax partials) alias xproj (dead after rnn_scan).
  char* ws = (char*)d_ws;
  u16*      emb16  = (u16*)(ws);                                  // 32768x1024 f16 = 64MB
  u16*      hidden = (u16*)(ws);                                  // 32768x2048 f16 = 128MB (alias)
  u16*      xproj  = (u16*)(ws + (size_t)128 * 1024 * 1024);      // [T][B][H] bf16 = 128MB
  float*    pm     = (float*)(ws + (size_t)128 * 1024 * 1024);    // 32768x32 f32 = 4MB (alias)
  float*    ps     = (float*)(ws + (size_t)136 * 1024 * 1024);    // 32768x32 f32 = 4MB (alias)
  u16*      WheadT = (u16*)(ws + (size_t)256 * 1024 * 1024);      // 8192x2048 f16 = 32MB
  u16*      WhT    = (u16*)(ws + (size_t)288 * 1024 * 1024);      // 2048x2048 f16 = 8MB
  u16*      WxT16  = (u16*)(ws + (size_t)304 * 1024 * 1024);      // 2048x1024 f16 = 4MB
  u16*      hbuf   = (u16*)(ws + (size_t)312 * 1024 * 1024);      // 2x64x2048 f16 = 512KB
  float*    nll    = (float*)(ws + (size_t)313 * 1024 * 1024);    // 32768 f32
  unsigned* sync   = (unsigned*)(ws + (size_t)313 * 1024 * 1024 + 128 * 1024);

  embed_cast_f16<<<Bb * Tt, 256, 0, stream>>>(W_E, idx, emb16);
  transpose_cast_f16<<<dim3(Hh / 32, Ee / 32), 256, 0, stream>>>(W_xh, WxT16, Ee, Hh);
  transpose_cast_f16<<<dim3(Hh / 32, Hh / 32), 256, 0, stream>>>(W_xh + (size_t)Ee * Hh, WhT, Hh, Hh);
  transpose_cast_f16<<<dim3(Vv / 32, Hh / 32), 256, 0, stream>>>(W_head, WheadT, Hh, Vv);
  h0_init<<<Bb, 256, 0, stream>>>(start, hbuf);
  hipMemsetAsync(sync, 0, 1024, stream);

  // xproj = emb_f16 @ Wx_f16 + b_xh   (K=1024, f16 MFMA, out bf16 t-major)
  gemm256<1, 1><<<dim3(128, 8), 512, 0, stream>>>(emb16, WxT16, b_xh, xproj, nullptr, nullptr,
                                                  Bb * Tt, Hh, 1024);

  // persistent scan: 256 blocks (1/CU), 512 threads, Wh resident in LDS (f16)
  rnn_scan<<<256, 512, 0, stream>>>(WhT, xproj, hbuf, hidden, sync);

  // logits = hidden_f16 @ Whead_f16 + b_head -> d_out, + fused softmax partials
  gemm256<0, 1><<<dim3(128, 32), 512, 0, stream>>>(hidden, WheadT, b_head, d_out, pm, ps,
                                                   Bb * Tt, Vv, 2048);

  nll_from_partials<<<Bb * Tt / 4, 256, 0, stream>>>(pm, ps, (const float*)d_out, tgt, nll);
  loss_reduce<<<1, 256, 0, stream>>>(nll, tgt, (float*)d_out + ((size_t)out_size - 1));
}